// Round 4
// baseline (194.792 us; speedup 1.0000x reference)
//
#include <hip/hip_runtime.h>

#define BATCH 64
#define NSAMP 1500
#define NFREQ 1251
#define NSEG  5
#define SEGLEN 300            // NSEG*SEGLEN == NSAMP, SEGLEN % 4 == 0
#define FBLK  256             // freqs per block
#define FCHUNKS 5             // ceil(NFREQ/FBLK); 5*256 = 1280 >= 1251
#define BLOCKS_PER_B (FCHUNKS * NSEG)   // 25

// workspace layout (bytes)
#define PCS_ELEMS   (BATCH * NSEG * NFREQ)          // float2 count
#define PER_OFF     (PCS_ELEMS * 8)                 // float[64]
#define CNT_OFF     (PER_OFF + 256)                 // unsigned[64]
#define CNT2_OFF    (CNT_OFF + 256)                 // unsigned[1]

// ---------------------------------------------------------------------------
// Fused kernel. Grid (BATCH, FCHUNKS, NSEG), 256 threads.
// Phase 1 (all blocks): Goertzel partial (C,S) for 256 freqs over one
//   300-sample segment; store to pcs[b][seg][f].
// Phase 2 (last block per b, via cnt[b] ticket): assemble psd row, softmax
//   log-gather at argmin|f_v - f_true|, store per_sample[b].
// Phase 3 (last block overall, via cnt2 ticket): mean over 64 rows -> out[0].
// Device-scope fences around the relaxed atomics give cross-XCD visibility
// (standard last-block pattern; counters zeroed by a 512 B memsetAsync).
// ---------------------------------------------------------------------------
__global__ __launch_bounds__(256) void fused_kernel(
    const float* __restrict__ x,          // [B,N]
    const float* __restrict__ fs,         // [B]
    const float* __restrict__ f_true,     // [B]
    const float* __restrict__ sampling_f, // [1]
    const float* __restrict__ f_range,    // f_min first
    float2* __restrict__ pcs,             // [B,NSEG,NFREQ]
    float* __restrict__ per_sample,       // [B]
    unsigned* __restrict__ cnt,           // [B]   zeroed
    unsigned* __restrict__ cnt2,          // [1]   zeroed
    float* __restrict__ out)              // [1]
{
    __shared__ float4 xs4[SEGLEN / 4];
    __shared__ float  psd_s[NFREQ];
    __shared__ float  smax[256];
    __shared__ float  ssum[256];
    __shared__ float  sdist[256];
    __shared__ int    sidx[256];
    __shared__ unsigned tick;

    const int b   = blockIdx.x;
    const int seg = blockIdx.z;
    const int tid = threadIdx.x;
    const int n0  = seg * SEGLEN;

    // ---- phase 1: Goertzel over this segment ----
    const float4* xg = reinterpret_cast<const float4*>(x + b * NSAMP + n0);
    for (int i = tid; i < SEGLEN / 4; i += FBLK) xs4[i] = xg[i];
    __syncthreads();

    const int fidx = blockIdx.y * FBLK + tid;

    // numpy arange fill semantics
    const float f_min = f_range[0];
    const float step  = sampling_f[0];
    const float delta = (f_min + step) - f_min;
    const float fv    = f_min + (float)fidx * delta;

    const float rho = fv / fs[b];                 // revolutions per sample
    float rf = rho - floorf(rho);
    const float coef = 2.0f * __builtin_amdgcn_cosf(rf);

    float s1 = 0.0f, s2 = 0.0f;
#pragma unroll 5
    for (int k = 0; k < SEGLEN / 4; ++k) {
        float4 v = xs4[k];
        float t;
        t = fmaf(coef, s1, v.x - s2); s2 = s1; s1 = t;
        t = fmaf(coef, s1, v.y - s2); s2 = s1; s1 = t;
        t = fmaf(coef, s1, v.z - s2); s2 = s1; s1 = t;
        t = fmaf(coef, s1, v.w - s2); s2 = s1; s1 = t;
    }

    float aM  = (float)SEGLEN * rho;        aM  -= floorf(aM);
    float aM1 = (float)(SEGLEN - 1) * rho;  aM1 -= floorf(aM1);
    float a0  = (float)n0 * rho;            a0  -= floorf(a0);
    const float cM  = __builtin_amdgcn_cosf(aM);
    const float sM  = __builtin_amdgcn_sinf(aM);
    const float cM1 = __builtin_amdgcn_cosf(aM1);
    const float sM1 = __builtin_amdgcn_sinf(aM1);
    const float c0  = __builtin_amdgcn_cosf(a0);
    const float s0  = __builtin_amdgcn_sinf(a0);

    const float Cl = cM1 * s1 - cM * s2;
    const float Sl = sM1 * s1 - sM * s2;
    const float C  = c0 * Cl - s0 * Sl;
    const float S  = s0 * Cl + c0 * Sl;

    if (fidx < NFREQ)
        pcs[(b * NSEG + seg) * NFREQ + fidx] = make_float2(C, S);

    // ---- ticket: last block for this b? ----
    __threadfence();                       // release partials (device scope)
    if (tid == 0) tick = atomicAdd(&cnt[b], 1u);
    __syncthreads();
    if (tick != BLOCKS_PER_B - 1) return;  // block-uniform
    __threadfence();                       // acquire others' partials

    // ---- phase 2: per-sample loss for row b ----
    const float ft = f_true[b];
    float vmax  = -INFINITY;
    float bestd = INFINITY;
    int   besti = NFREQ;
    for (int i = tid; i < NFREQ; i += 256) {
        float c = 0.0f, s = 0.0f;
#pragma unroll
        for (int g = 0; g < NSEG; ++g) {
            float2 v = pcs[(b * NSEG + g) * NFREQ + i];
            c += v.x; s += v.y;
        }
        float v = fmaf(c, c, s * s);
        psd_s[i] = v;
        vmax = fmaxf(vmax, v);
        float fg = f_min + (float)i * delta;
        float d  = fabsf(fg - ft);
        if (d < bestd) { bestd = d; besti = i; }    // per-thread first min
    }
    smax[tid] = vmax; sdist[tid] = bestd; sidx[tid] = besti;
    __syncthreads();
    for (int s = 128; s > 0; s >>= 1) {
        if (tid < s) {
            smax[tid] = fmaxf(smax[tid], smax[tid + s]);
            float d2 = sdist[tid + s]; int i2 = sidx[tid + s];
            if (d2 < sdist[tid] || (d2 == sdist[tid] && i2 < sidx[tid])) {
                sdist[tid] = d2; sidx[tid] = i2;    // np.argmin: first occurrence
            }
        }
        __syncthreads();
    }
    const float gmax = smax[0];
    const int   idx  = sidx[0];

    float se = 0.0f;
    for (int i = tid; i < NFREQ; i += 256) se += __expf(psd_s[i] - gmax);
    ssum[tid] = se;
    __syncthreads();
    for (int s = 128; s > 0; s >>= 1) {
        if (tid < s) ssum[tid] += ssum[tid + s];
        __syncthreads();
    }

    if (tid == 0) {
        float sm = __expf(psd_s[idx] - gmax) / ssum[0];
        per_sample[b] = -logf(sm + 1e-8f);
    }

    // ---- ticket: last row overall? ----
    __threadfence();                       // release per_sample[b]
    if (tid == 0) tick = atomicAdd(cnt2, 1u);
    __syncthreads();
    if (tick != BATCH - 1) return;
    __threadfence();                       // acquire all per_sample

    // ---- phase 3: mean over 64 rows ----
    if (tid < 64) {
        float v = per_sample[tid];
        for (int off = 32; off > 0; off >>= 1) v += __shfl_down(v, off);
        if (tid == 0) out[0] = v * (1.0f / (float)BATCH);
    }
}

extern "C" void kernel_launch(void* const* d_in, const int* in_sizes, int n_in,
                              void* d_out, int out_size, void* d_ws, size_t ws_size,
                              hipStream_t stream) {
    const float* x          = (const float*)d_in[0];
    const float* f_true     = (const float*)d_in[1];
    const float* fs         = (const float*)d_in[2];
    // d_in[3] = deltas (unused)
    const float* sampling_f = (const float*)d_in[4];
    const float* f_range    = (const float*)d_in[5];

    char* ws = (char*)d_ws;
    float2*   pcs        = (float2*)ws;
    float*    per_sample = (float*)(ws + PER_OFF);
    unsigned* cnt        = (unsigned*)(ws + CNT_OFF);
    unsigned* cnt2       = (unsigned*)(ws + CNT2_OFF);

    // zero the two ticket counters (cnt[64] + cnt2); ~free tiny dispatch
    hipMemsetAsync(ws + CNT_OFF, 0, 512, stream);

    dim3 g(BATCH, FCHUNKS, NSEG);          // 64 x 5 x 5 = 1600 blocks
    fused_kernel<<<g, FBLK, 0, stream>>>(x, fs, f_true, sampling_f, f_range,
                                         pcs, per_sample, cnt, cnt2,
                                         (float*)d_out);
}

// Round 5
// 81.382 us; speedup vs baseline: 2.3936x; 2.3936x over previous
//
#include <hip/hip_runtime.h>

#define BATCH 64
#define NSAMP 1500
#define NFREQ 1251
#define NSEG  5
#define SEGLEN 300            // NSEG*SEGLEN == NSAMP, SEGLEN % 4 == 0
#define FBLK  256             // freqs per block
#define FCHUNKS 5             // 5*256 = 1280 >= 1251

// ---------------------------------------------------------------------------
// Kernel 1: full Goertzel per (b, fchunk) block. Each thread runs FIVE
// independent 300-sample Goertzel recurrences (one per time segment),
// interleaved for ILP (the 2-op/sample chain has 4-cyc FMA latency; 5
// independent chains keep the SIMD issue-bound). Segment results are
// rotated by their start phase and summed in-register (same g=0..4 order
// as the previous 2-kernel version -> identical numerics), then
// psd[b,f] = C^2 + S^2 is stored directly. No partials round-trip.
// Trig note: coef/cM/sM/cM1/sM1 depend only on rho (same M for all segs);
// only the 5 start-phase rotations (c0,s0) differ. All trig in REVOLUTIONS
// (v_sin/v_cos semantics, validated rounds 1-3).
// Thread (0,0,0) zeroes d_out for kernel 2's atomicAdd (stream-ordered).
// ---------------------------------------------------------------------------
__global__ __launch_bounds__(256) void goertzel_kernel(
    const float* __restrict__ x,          // [B,N]
    const float* __restrict__ fs,         // [B]
    const float* __restrict__ sampling_f, // [1]
    const float* __restrict__ f_range,    // f_min first
    float* __restrict__ psd,              // [B,NFREQ]
    float* __restrict__ out)              // [1] zeroed here
{
    __shared__ float4 xs4[NSAMP / 4];     // 375 float4 = 6 KB
    const int b   = blockIdx.x;
    const int tid = threadIdx.x;

    if (b == 0 && blockIdx.y == 0 && tid == 0) out[0] = 0.0f;

    const float4* xg = reinterpret_cast<const float4*>(x + b * NSAMP);
    for (int i = tid; i < NSAMP / 4; i += FBLK) xs4[i] = xg[i];
    __syncthreads();

    const int fidx = blockIdx.y * FBLK + tid;

    // numpy arange fill semantics
    const float f_min = f_range[0];
    const float step  = sampling_f[0];
    const float delta = (f_min + step) - f_min;
    const float fv    = f_min + (float)fidx * delta;

    const float rho = fv / fs[b];                 // revolutions per sample
    float rf = rho - floorf(rho);
    const float coef = 2.0f * __builtin_amdgcn_cosf(rf);

    float s1[NSEG], s2[NSEG];
#pragma unroll
    for (int g = 0; g < NSEG; ++g) { s1[g] = 0.0f; s2[g] = 0.0f; }

#pragma unroll 3
    for (int k = 0; k < SEGLEN / 4; ++k) {
#pragma unroll
        for (int g = 0; g < NSEG; ++g) {
            float4 v = xs4[g * (SEGLEN / 4) + k];
            float t;
            t = fmaf(coef, s1[g], v.x - s2[g]); s2[g] = s1[g]; s1[g] = t;
            t = fmaf(coef, s1[g], v.y - s2[g]); s2[g] = s1[g]; s1[g] = t;
            t = fmaf(coef, s1[g], v.z - s2[g]); s2[g] = s1[g]; s1[g] = t;
            t = fmaf(coef, s1[g], v.w - s2[g]); s2[g] = s1[g]; s1[g] = t;
        }
    }

    // segment-independent extraction trig (M = SEGLEN for every segment)
    float aM  = (float)SEGLEN * rho;        aM  -= floorf(aM);
    float aM1 = (float)(SEGLEN - 1) * rho;  aM1 -= floorf(aM1);
    const float cM  = __builtin_amdgcn_cosf(aM);
    const float sM  = __builtin_amdgcn_sinf(aM);
    const float cM1 = __builtin_amdgcn_cosf(aM1);
    const float sM1 = __builtin_amdgcn_sinf(aM1);

    float C = 0.0f, S = 0.0f;
#pragma unroll
    for (int g = 0; g < NSEG; ++g) {
        float a0 = (float)(g * SEGLEN) * rho;  a0 -= floorf(a0);
        const float c0 = __builtin_amdgcn_cosf(a0);
        const float s0 = __builtin_amdgcn_sinf(a0);
        const float Cl = cM1 * s1[g] - cM * s2[g];
        const float Sl = sM1 * s1[g] - sM * s2[g];
        C += c0 * Cl - s0 * Sl;               // g-ascending, same order as before
        S += s0 * Cl + c0 * Sl;
    }

    if (fidx < NFREQ)
        psd[b * NFREQ + fidx] = fmaf(C, C, S * S);
}

// ---------------------------------------------------------------------------
// Kernel 2: per-sample softmax log-gather + fused mean (atomicAdd into out,
// zeroed by kernel 1). Wave-shuffle reductions, 2 barriers total.
// ---------------------------------------------------------------------------
__global__ __launch_bounds__(256) void loss_kernel(
    const float* __restrict__ psd,        // [B,NFREQ]
    const float* __restrict__ f_true,     // [B]
    const float* __restrict__ sampling_f,
    const float* __restrict__ f_range,
    float* __restrict__ out)              // [1]
{
    const int b    = blockIdx.x;
    const int tid  = threadIdx.x;
    const int wave = tid >> 6;
    const int lane = tid & 63;

    __shared__ float psd_s[NFREQ];
    __shared__ float wmax[4];
    __shared__ float wdist[4];
    __shared__ int   widx[4];
    __shared__ float wsum[4];
    __shared__ float s_gmax;
    __shared__ int   s_idx;

    const float f_min = f_range[0];
    const float step  = sampling_f[0];
    const float delta = (f_min + step) - f_min;
    const float ft    = f_true[b];
    const float* p    = psd + b * NFREQ;

    float vmax  = -INFINITY;
    float bestd = INFINITY;
    int   besti = NFREQ;
    for (int i = tid; i < NFREQ; i += 256) {
        float v = p[i];
        psd_s[i] = v;
        vmax = fmaxf(vmax, v);
        float fg = f_min + (float)i * delta;
        float d  = fabsf(fg - ft);
        if (d < bestd) { bestd = d; besti = i; }   // per-thread first min
    }
    // wave-level reduce (64 lanes)
    for (int off = 32; off > 0; off >>= 1) {
        float m2 = __shfl_down(vmax, off);
        float d2 = __shfl_down(bestd, off);
        int   i2 = __shfl_down(besti, off);
        vmax = fmaxf(vmax, m2);
        if (d2 < bestd || (d2 == bestd && i2 < besti)) { bestd = d2; besti = i2; }
    }
    if (lane == 0) { wmax[wave] = vmax; wdist[wave] = bestd; widx[wave] = besti; }
    __syncthreads();
    if (tid == 0) {
        float gm = wmax[0]; float bd = wdist[0]; int bi = widx[0];
#pragma unroll
        for (int w = 1; w < 4; ++w) {
            gm = fmaxf(gm, wmax[w]);
            if (wdist[w] < bd || (wdist[w] == bd && widx[w] < bi)) {
                bd = wdist[w]; bi = widx[w];       // np.argmin: first occurrence
            }
        }
        s_gmax = gm; s_idx = bi;
    }
    __syncthreads();
    const float gmax = s_gmax;
    const int   idx  = s_idx;

    float se = 0.0f;
    for (int i = tid; i < NFREQ; i += 256) se += __expf(psd_s[i] - gmax);
    for (int off = 32; off > 0; off >>= 1) se += __shfl_down(se, off);
    if (lane == 0) wsum[wave] = se;
    __syncthreads();

    if (tid == 0) {
        float sumexp = wsum[0] + wsum[1] + wsum[2] + wsum[3];
        float sm = __expf(psd_s[idx] - gmax) / sumexp;
        float per = -logf(sm + 1e-8f);
        atomicAdd(out, per * (1.0f / (float)BATCH));
    }
}

extern "C" void kernel_launch(void* const* d_in, const int* in_sizes, int n_in,
                              void* d_out, int out_size, void* d_ws, size_t ws_size,
                              hipStream_t stream) {
    const float* x          = (const float*)d_in[0];
    const float* f_true     = (const float*)d_in[1];
    const float* fs         = (const float*)d_in[2];
    // d_in[3] = deltas (unused)
    const float* sampling_f = (const float*)d_in[4];
    const float* f_range    = (const float*)d_in[5];

    float* psd = (float*)d_ws;             // [B*NFREQ] = 320 KB

    dim3 g1(BATCH, FCHUNKS);               // 64 x 5 = 320 blocks x 4 waves
    goertzel_kernel<<<g1, FBLK, 0, stream>>>(x, fs, sampling_f, f_range, psd,
                                             (float*)d_out);
    loss_kernel<<<BATCH, 256, 0, stream>>>(psd, f_true, sampling_f, f_range,
                                           (float*)d_out);
}

// Round 6
// 76.395 us; speedup vs baseline: 2.5498x; 1.0653x over previous
//
#include <hip/hip_runtime.h>

#define BATCH 64
#define NSAMP 1500
#define NFREQ 1251
#define NSEG  5
#define SEGLEN 300            // NSEG*SEGLEN == NSAMP, SEGLEN % 4 == 0
#define FBLK  256             // freqs per block
#define FCHUNKS 5             // 5*256 = 1280 >= 1251

// ---------------------------------------------------------------------------
// Kernel 1 (round-3 config, best measured): Goertzel partials.
// Grid (B, FCHUNKS, NSEG) = 1600 blocks x 4 waves -> 25 waves/CU.
//   s_k = x_k + 2cos(w) s_{k-1} - s_{k-2}
//   C_loc = cos((M-1)w) s1 - cos(Mw) s2 ; S_loc = sin((M-1)w) s1 - sin(Mw) s2
// rotated by segment-start phase. Trig in REVOLUTIONS (v_sin/v_cos).
// Thread (0,0,0) zeroes d_out for kernel 2's atomicAdd (stream-ordered).
// ---------------------------------------------------------------------------
__global__ __launch_bounds__(256) void goertzel_kernel(
    const float* __restrict__ x,          // [B,N]
    const float* __restrict__ fs,         // [B]
    const float* __restrict__ sampling_f, // [1]
    const float* __restrict__ f_range,    // f_min first
    float2* __restrict__ pcs,             // [B,NSEG,NFREQ] partial (C,S)
    float* __restrict__ out)              // [1] zeroed here
{
    __shared__ float4 xs4[SEGLEN / 4];    // 75 float4
    const int b   = blockIdx.x;
    const int seg = blockIdx.z;
    const int tid = threadIdx.x;
    const int n0  = seg * SEGLEN;

    if (b == 0 && seg == 0 && blockIdx.y == 0 && tid == 0) out[0] = 0.0f;

    const float4* xg = reinterpret_cast<const float4*>(x + b * NSAMP + n0);
    for (int i = tid; i < SEGLEN / 4; i += FBLK) xs4[i] = xg[i];
    __syncthreads();

    const int fidx = blockIdx.y * FBLK + tid;
    if (fidx >= NFREQ) return;

    // numpy arange fill semantics
    const float f_min = f_range[0];
    const float step  = sampling_f[0];
    const float delta = (f_min + step) - f_min;
    const float fv    = f_min + (float)fidx * delta;

    const float rho = fv / fs[b];                 // revolutions per sample
    float rf = rho - floorf(rho);
    const float coef = 2.0f * __builtin_amdgcn_cosf(rf);

    float s1 = 0.0f, s2 = 0.0f;
#pragma unroll 5
    for (int k = 0; k < SEGLEN / 4; ++k) {
        float4 v = xs4[k];
        float t;
        t = fmaf(coef, s1, v.x - s2); s2 = s1; s1 = t;
        t = fmaf(coef, s1, v.y - s2); s2 = s1; s1 = t;
        t = fmaf(coef, s1, v.z - s2); s2 = s1; s1 = t;
        t = fmaf(coef, s1, v.w - s2); s2 = s1; s1 = t;
    }

    float aM  = (float)SEGLEN * rho;        aM  -= floorf(aM);
    float aM1 = (float)(SEGLEN - 1) * rho;  aM1 -= floorf(aM1);
    float a0  = (float)n0 * rho;            a0  -= floorf(a0);
    const float cM  = __builtin_amdgcn_cosf(aM);
    const float sM  = __builtin_amdgcn_sinf(aM);
    const float cM1 = __builtin_amdgcn_cosf(aM1);
    const float sM1 = __builtin_amdgcn_sinf(aM1);
    const float c0  = __builtin_amdgcn_cosf(a0);
    const float s0  = __builtin_amdgcn_sinf(a0);

    const float Cl = cM1 * s1 - cM * s2;
    const float Sl = sM1 * s1 - sM * s2;
    const float C  = c0 * Cl - s0 * Sl;
    const float S  = s0 * Cl + c0 * Sl;

    pcs[(b * NSEG + seg) * NFREQ + fidx] = make_float2(C, S);
}

// ---------------------------------------------------------------------------
// Kernel 2 (round-5 style, shuffle-based): assemble psd from partials
// (g-ascending, same numerics as rounds 2-4), per-sample softmax
// log-gather at argmin|f_v - f_true|, fused mean via atomicAdd.
// ---------------------------------------------------------------------------
__global__ __launch_bounds__(256) void loss_kernel(
    const float2* __restrict__ pcs,       // [B,NSEG,NFREQ]
    const float* __restrict__ f_true,     // [B]
    const float* __restrict__ sampling_f,
    const float* __restrict__ f_range,
    float* __restrict__ out)              // [1]
{
    const int b    = blockIdx.x;
    const int tid  = threadIdx.x;
    const int wave = tid >> 6;
    const int lane = tid & 63;

    __shared__ float psd_s[NFREQ];
    __shared__ float wmax[4];
    __shared__ float wdist[4];
    __shared__ int   widx[4];
    __shared__ float wsum[4];
    __shared__ float s_gmax;
    __shared__ int   s_idx;

    const float f_min = f_range[0];
    const float step  = sampling_f[0];
    const float delta = (f_min + step) - f_min;
    const float ft    = f_true[b];

    float vmax  = -INFINITY;
    float bestd = INFINITY;
    int   besti = NFREQ;
    for (int i = tid; i < NFREQ; i += 256) {
        float c = 0.0f, s = 0.0f;
#pragma unroll
        for (int g = 0; g < NSEG; ++g) {
            float2 v = pcs[(b * NSEG + g) * NFREQ + i];
            c += v.x; s += v.y;
        }
        float v = fmaf(c, c, s * s);
        psd_s[i] = v;
        vmax = fmaxf(vmax, v);
        float fg = f_min + (float)i * delta;
        float d  = fabsf(fg - ft);
        if (d < bestd) { bestd = d; besti = i; }   // per-thread first min
    }
    // wave-level reduce (64 lanes); lower tid wins ties -> np first-occurrence
    for (int off = 32; off > 0; off >>= 1) {
        float m2 = __shfl_down(vmax, off);
        float d2 = __shfl_down(bestd, off);
        int   i2 = __shfl_down(besti, off);
        vmax = fmaxf(vmax, m2);
        if (d2 < bestd || (d2 == bestd && i2 < besti)) { bestd = d2; besti = i2; }
    }
    if (lane == 0) { wmax[wave] = vmax; wdist[wave] = bestd; widx[wave] = besti; }
    __syncthreads();
    if (tid == 0) {
        float gm = wmax[0]; float bd = wdist[0]; int bi = widx[0];
#pragma unroll
        for (int w = 1; w < 4; ++w) {
            gm = fmaxf(gm, wmax[w]);
            if (wdist[w] < bd || (wdist[w] == bd && widx[w] < bi)) {
                bd = wdist[w]; bi = widx[w];
            }
        }
        s_gmax = gm; s_idx = bi;
    }
    __syncthreads();
    const float gmax = s_gmax;
    const int   idx  = s_idx;

    float se = 0.0f;
    for (int i = tid; i < NFREQ; i += 256) se += __expf(psd_s[i] - gmax);
    for (int off = 32; off > 0; off >>= 1) se += __shfl_down(se, off);
    if (lane == 0) wsum[wave] = se;
    __syncthreads();

    if (tid == 0) {
        float sumexp = wsum[0] + wsum[1] + wsum[2] + wsum[3];
        float sm = __expf(psd_s[idx] - gmax) / sumexp;
        float per = -logf(sm + 1e-8f);
        atomicAdd(out, per * (1.0f / (float)BATCH));
    }
}

extern "C" void kernel_launch(void* const* d_in, const int* in_sizes, int n_in,
                              void* d_out, int out_size, void* d_ws, size_t ws_size,
                              hipStream_t stream) {
    const float* x          = (const float*)d_in[0];
    const float* f_true     = (const float*)d_in[1];
    const float* fs         = (const float*)d_in[2];
    // d_in[3] = deltas (unused)
    const float* sampling_f = (const float*)d_in[4];
    const float* f_range    = (const float*)d_in[5];

    float2* pcs = (float2*)d_ws;           // [B*NSEG*NFREQ] float2 = 3.2 MB

    dim3 g1(BATCH, FCHUNKS, NSEG);         // 64 x 5 x 5 = 1600 blocks x 4 waves
    goertzel_kernel<<<g1, FBLK, 0, stream>>>(x, fs, sampling_f, f_range, pcs,
                                             (float*)d_out);
    loss_kernel<<<BATCH, 256, 0, stream>>>(pcs, f_true, sampling_f, f_range,
                                           (float*)d_out);
}

// Round 7
// 75.637 us; speedup vs baseline: 2.5754x; 1.0100x over previous
//
#include <hip/hip_runtime.h>

#define BATCH 64
#define NSAMP 1500
#define NFREQ 1251
#define NSEG  5
#define SEGLEN 300            // NSEG*SEGLEN == NSAMP, SEGLEN % 4 == 0
#define FBLK  256             // freqs per block
#define FCHUNKS 5             // 5*256 = 1280 >= 1251

// ---------------------------------------------------------------------------
// Kernel 1 (unchanged from round 6 — measured best config): Goertzel partials.
// Grid (B, FCHUNKS, NSEG) = 1600 blocks x 4 waves -> 25 waves/CU.
//   s_k = x_k + 2cos(w) s_{k-1} - s_{k-2}
//   C_loc = cos((M-1)w) s1 - cos(Mw) s2 ; S_loc = sin((M-1)w) s1 - sin(Mw) s2
// rotated by segment-start phase. Trig in REVOLUTIONS (v_sin/v_cos).
// Thread (0,0,0) zeroes d_out for kernel 2's atomicAdd (stream-ordered).
// ---------------------------------------------------------------------------
__global__ __launch_bounds__(256) void goertzel_kernel(
    const float* __restrict__ x,          // [B,N]
    const float* __restrict__ fs,         // [B]
    const float* __restrict__ sampling_f, // [1]
    const float* __restrict__ f_range,    // f_min first
    float2* __restrict__ pcs,             // [B,NSEG,NFREQ] partial (C,S)
    float* __restrict__ out)              // [1] zeroed here
{
    __shared__ float4 xs4[SEGLEN / 4];    // 75 float4
    const int b   = blockIdx.x;
    const int seg = blockIdx.z;
    const int tid = threadIdx.x;
    const int n0  = seg * SEGLEN;

    if (b == 0 && seg == 0 && blockIdx.y == 0 && tid == 0) out[0] = 0.0f;

    const float4* xg = reinterpret_cast<const float4*>(x + b * NSAMP + n0);
    for (int i = tid; i < SEGLEN / 4; i += FBLK) xs4[i] = xg[i];
    __syncthreads();

    const int fidx = blockIdx.y * FBLK + tid;
    if (fidx >= NFREQ) return;

    // numpy arange fill semantics
    const float f_min = f_range[0];
    const float step  = sampling_f[0];
    const float delta = (f_min + step) - f_min;
    const float fv    = f_min + (float)fidx * delta;

    const float rho = fv / fs[b];                 // revolutions per sample
    float rf = rho - floorf(rho);
    const float coef = 2.0f * __builtin_amdgcn_cosf(rf);

    float s1 = 0.0f, s2 = 0.0f;
#pragma unroll 5
    for (int k = 0; k < SEGLEN / 4; ++k) {
        float4 v = xs4[k];
        float t;
        t = fmaf(coef, s1, v.x - s2); s2 = s1; s1 = t;
        t = fmaf(coef, s1, v.y - s2); s2 = s1; s1 = t;
        t = fmaf(coef, s1, v.z - s2); s2 = s1; s1 = t;
        t = fmaf(coef, s1, v.w - s2); s2 = s1; s1 = t;
    }

    float aM  = (float)SEGLEN * rho;        aM  -= floorf(aM);
    float aM1 = (float)(SEGLEN - 1) * rho;  aM1 -= floorf(aM1);
    float a0  = (float)n0 * rho;            a0  -= floorf(a0);
    const float cM  = __builtin_amdgcn_cosf(aM);
    const float sM  = __builtin_amdgcn_sinf(aM);
    const float cM1 = __builtin_amdgcn_cosf(aM1);
    const float sM1 = __builtin_amdgcn_sinf(aM1);
    const float c0  = __builtin_amdgcn_cosf(a0);
    const float s0  = __builtin_amdgcn_sinf(a0);

    const float Cl = cM1 * s1 - cM * s2;
    const float Sl = sM1 * s1 - sM * s2;
    const float C  = c0 * Cl - s0 * Sl;
    const float S  = s0 * Cl + c0 * Sl;

    pcs[(b * NSEG + seg) * NFREQ + fidx] = make_float2(C, S);
}

// ---------------------------------------------------------------------------
// Kernel 2: single-pass loss.
//  - idx computed in CLOSED FORM: f_values are monotone increasing, so
//    argmin|f_v - ft| lies within +-2 of round((ft-f_min)/delta). The 5
//    candidates are evaluated with the identical fp32 expression the
//    reference grid uses (f_min + i*delta), first-min tie rule ->
//    bit-exact np.argmin without scanning 1251 entries.
//  - online softmax (running m, l) in one pass, shuffle-combined:
//    no LDS psd array, no second pass.
//  - the thread that owns idx records psd[idx] to LDS.
//  Fused mean via atomicAdd into out (zeroed by kernel 1).
// ---------------------------------------------------------------------------
__global__ __launch_bounds__(256) void loss_kernel(
    const float2* __restrict__ pcs,       // [B,NSEG,NFREQ]
    const float* __restrict__ f_true,     // [B]
    const float* __restrict__ sampling_f,
    const float* __restrict__ f_range,
    float* __restrict__ out)              // [1]
{
    const int b    = blockIdx.x;
    const int tid  = threadIdx.x;
    const int wave = tid >> 6;
    const int lane = tid & 63;

    __shared__ float wm[4];
    __shared__ float wl[4];
    __shared__ float s_pidx;

    const float f_min = f_range[0];
    const float step  = sampling_f[0];
    const float delta = (f_min + step) - f_min;
    const float ft    = f_true[b];

    // closed-form argmin (np first-occurrence semantics)
    int iq = (int)((ft - f_min) / delta + 0.5f);
    int lo = iq - 2; if (lo < 0) lo = 0;
    int hi = iq + 2; if (hi > NFREQ - 1) hi = NFREQ - 1;
    int   idx   = lo;
    float bestd = fabsf((f_min + (float)lo * delta) - ft);
    for (int i = lo + 1; i <= hi; ++i) {
        float d = fabsf((f_min + (float)i * delta) - ft);
        if (d < bestd) { bestd = d; idx = i; }     // strict < : first occurrence
    }

    // one pass: assemble psd element, online max/sumexp
    float m = -INFINITY, l = 0.0f;
    for (int i = tid; i < NFREQ; i += 256) {
        float c = 0.0f, s = 0.0f;
#pragma unroll
        for (int g = 0; g < NSEG; ++g) {
            float2 v = pcs[(b * NSEG + g) * NFREQ + i];
            c += v.x; s += v.y;
        }
        float v = fmaf(c, c, s * s);
        if (i == idx) s_pidx = v;                  // exactly one thread
        float mn = fmaxf(m, v);
        l = l * __expf(m - mn) + __expf(v - mn);
        m = mn;
    }
    // wave combine (64 lanes)
    for (int off = 32; off > 0; off >>= 1) {
        float m2 = __shfl_down(m, off);
        float l2 = __shfl_down(l, off);
        float mn = fmaxf(m, m2);
        l = l * __expf(m - mn) + l2 * __expf(m2 - mn);
        m = mn;
    }
    if (lane == 0) { wm[wave] = m; wl[wave] = l; }
    __syncthreads();

    if (tid == 0) {
        float gm = wm[0], gl = wl[0];
#pragma unroll
        for (int w = 1; w < 4; ++w) {
            float mn = fmaxf(gm, wm[w]);
            gl = gl * __expf(gm - mn) + wl[w] * __expf(wm[w] - mn);
            gm = mn;
        }
        float sm  = __expf(s_pidx - gm) / gl;
        float per = -logf(sm + 1e-8f);
        atomicAdd(out, per * (1.0f / (float)BATCH));
    }
}

extern "C" void kernel_launch(void* const* d_in, const int* in_sizes, int n_in,
                              void* d_out, int out_size, void* d_ws, size_t ws_size,
                              hipStream_t stream) {
    const float* x          = (const float*)d_in[0];
    const float* f_true     = (const float*)d_in[1];
    const float* fs         = (const float*)d_in[2];
    // d_in[3] = deltas (unused)
    const float* sampling_f = (const float*)d_in[4];
    const float* f_range    = (const float*)d_in[5];

    float2* pcs = (float2*)d_ws;           // [B*NSEG*NFREQ] float2 = 3.2 MB

    dim3 g1(BATCH, FCHUNKS, NSEG);         // 64 x 5 x 5 = 1600 blocks x 4 waves
    goertzel_kernel<<<g1, FBLK, 0, stream>>>(x, fs, sampling_f, f_range, pcs,
                                             (float*)d_out);
    loss_kernel<<<BATCH, 256, 0, stream>>>(pcs, f_true, sampling_f, f_range,
                                           (float*)d_out);
}